// Round 4
// baseline (2526.616 us; speedup 1.0000x reference)
//
#include <hip/hip_runtime.h>
#include <math.h>

// Problem constants
#define DD 256            // latent dim
#define KK 8192           // codebook size
#define NN 16384          // rows
#define MT 16             // rows per block (main kernel; 2 row-groups x 8)
#define RPW 8             // rows per wave (keeps fma:overhead ratio)
#define NT 512            // codebook cols per chunk (lane + 64*j, j 0..7)
#define NCHG 8            // chunks per group (16 total / 2 groups)
#define DT 4              // d-slice floats per epoch (1 d4-step)
#define NSL (DD / DT)     // 64 slices per chunk
#define NEPG (NCHG * NSL) // 512 epochs per group
#define NBM (NN / MT)     // 1024 main blocks x 256 thr -> EXACTLY 4 blocks/CU
#define NBLOCKS 512       // gather/partial blocks (old verified 32-row geometry)
#define CBUFF 2048        // floats per C buffer (512 cols x 4 d) = 8 KB
#define RSTRIDE 260       // rowsumsq staging stride (unchanged, verified)

// Output layout (all float32, concatenated in reference return order)
#define OUT_IDS   0
#define OUT_Q     16384
#define OUT_ST    4210688          // 16384 + 4194304
#define OUT_COMMIT 8404992
#define OUT_CBL    8404993
#define OUT_PERP   8404994

// ---------------------------------------------------------------------------
// async global->LDS DMA: lane i's 16B lands at ldsbase + i*16 (contiguous 1KB).
// Global source address is PER-LANE -> layout shuffles live on the source side.
// ---------------------------------------------------------------------------
__device__ __forceinline__ void gl2lds16(const float* g, float* l) {
    __builtin_amdgcn_global_load_lds(
        (const __attribute__((address_space(1))) float*)g,
        (__attribute__((address_space(3))) float*)l, 16, 0, 0);
}

// readlane: pull a float from a given lane into an SGPR (uniform). Bit-exact.
__device__ __forceinline__ float rlane(float v, int l) {
    return __int_as_float(__builtin_amdgcn_readlane(__float_as_int(v), l));
}

// ---------------------------------------------------------------------------
// numpy pairwise-sum replica for sum of squares (verified bit-exact)
// ---------------------------------------------------------------------------
__device__ __forceinline__ float np_block128_sumsq(const float* p) {
    #pragma clang fp contract(off)
    float r0 = p[0] * p[0], r1 = p[1] * p[1], r2 = p[2] * p[2], r3 = p[3] * p[3];
    float r4 = p[4] * p[4], r5 = p[5] * p[5], r6 = p[6] * p[6], r7 = p[7] * p[7];
    for (int i = 8; i < 128; i += 8) {
        r0 = r0 + p[i + 0] * p[i + 0];
        r1 = r1 + p[i + 1] * p[i + 1];
        r2 = r2 + p[i + 2] * p[i + 2];
        r3 = r3 + p[i + 3] * p[i + 3];
        r4 = r4 + p[i + 4] * p[i + 4];
        r5 = r5 + p[i + 5] * p[i + 5];
        r6 = r6 + p[i + 6] * p[i + 6];
        r7 = r7 + p[i + 7] * p[i + 7];
    }
    return ((r0 + r1) + (r2 + r3)) + ((r4 + r5) + (r6 + r7));
}

__device__ __forceinline__ float np_pairwise256_sumsq(const float* a) {
    #pragma clang fp contract(off)
    float s0 = np_block128_sumsq(a);
    float s1 = np_block128_sumsq(a + 128);
    return s0 + s1;
}

// ---------------------------------------------------------------------------
// Kernel 1: per-row sum of squares, numpy-pairwise-exact (unchanged, verified)
// ---------------------------------------------------------------------------
__global__ __launch_bounds__(256) void rowsumsq(const float* __restrict__ A,
                                                float* __restrict__ out) {
    __shared__ __align__(16) float sA[64][RSTRIDE];
    const int tid = threadIdx.x;
    const int base = blockIdx.x * 64;
    #pragma unroll
    for (int i = 0; i < 16; ++i) {
        int g = i * 256 + tid;
        int row = g >> 6, d4 = g & 63;
        float4 v = reinterpret_cast<const float4*>(A)[(size_t)(base + row) * (DD / 4) + d4];
        *reinterpret_cast<float4*>(&sA[row][d4 * 4]) = v;
    }
    __syncthreads();
    if (tid < 64) out[base + tid] = np_pairwise256_sumsq(sA[tid]);
}

// ---------------------------------------------------------------------------
// Kernel 2: main VQ distance+argmin kernel. 1024 blocks x 256 threads (4 waves)
//   -> EXACTLY 4 blocks/CU = 16 waves/CU = 4 waves/SIMD, zero tail.
//   ROUND-4 RESTRUCTURE, from the R0/R1/R3 occupancy law: launch_bounds arg2
//   acts as blocks/CU for REGALLOC but waves/EU for RESIDENCY. 8-wave blocks
//   can't satisfy both (arg2=4 -> 64 VGPR spill; arg2=2 -> 1 block resident).
//   4-wave blocks: (256,4) -> VGPR<=128 (this loop needs ~100, R3 evidence)
//   AND 4 blocks/CU; resource math agrees independently (LDS 33KB x4 = 133
//   <= 160 KB, VGPR ~110 -> 4 waves/SIMD), so residency holds under either
//   launch-bounds model.
//   - MT=16 rows (2 row-groups x 8), K-split 2-way (2 chunk-groups x 2 waves).
//   - sX LDS stage DROPPED: xp float4 read directly from global X once per 8
//     epochs (X block is 16 KB, L2-hot; 8x128B segments; latency hidden by
//     16 waves). Saves 16 KB LDS + the X staging DMA.
//   - C stream: per group, double-buffered 8 KB slices (DT=4), gl2lds DMA,
//     1 barrier/epoch (same verified sync structure as R0/R3).
//   - gather/MSE epilogue moved to vq_gather (old 512-block geometry) for
//     bit-exact partial sums; this kernel outputs ids + histogram only.
//   Per-(row,col) fp32 fma chain (d = 0..255, x/y/z/w order) unchanged ->
//   scores bit-exact; argmin first-index ties preserved (ascending chunks per
//   group; cross-group merge strict-less favors group 0 = lower cols).
// ---------------------------------------------------------------------------
__global__ __launch_bounds__(256, 4) void vq_main(const float* __restrict__ X,
                                                  const float* __restrict__ CB,
                                                  const float* __restrict__ c2,
                                                  const float* __restrict__ x2,
                                                  const float* __restrict__ mask,
                                                  float* __restrict__ out,
                                                  float* __restrict__ hist) {
    __shared__ __align__(16) float sC[4 * CBUFF];   // 32 KB: 2 groups x dbuf x 8 KB
    __shared__ float gbest[2][MT];
    __shared__ int   gidx[2][MT];

    const int tid  = threadIdx.x;
    const int lane = tid & 63;
    const int wid  = tid >> 6;                                  // 0..3
    const int widu = __builtin_amdgcn_readfirstlane(wid);       // uniform copy
    const int g    = wid >> 1;        // chunk-group (0: cols 0..4095, 1: 4096..8191)
    const int gu   = widu >> 1;
    const int wg   = wid & 1;         // row-group within block (8 rows each)
    const int wgu  = widu & 1;
    const int block_row = blockIdx.x * MT;

    // ---- C staging source offsets: unit u = col (single d4-plane).
    //      Group's 8 KB/epoch staged by its 2 waves -> 4 calls/wave.
    unsigned coff[4];
    #pragma unroll
    for (int k = 0; k < 4; ++k)
        coff[k] = ((wgu * 4u + (unsigned)k) * 64u + (unsigned)lane) * DD;

    const float* CBg = CB + (size_t)gu * NCHG * NT * DD;   // group's chunk base
    float* sCg = &sC[gu * 2 * CBUFF];                      // group's buffer pair
    #pragma unroll
    for (int k = 0; k < 4; ++k)     // epoch 0 (group chunk 0, sl 0) -> buf 0
        gl2lds16(CBg + coff[k], sCg + (wgu * 4 + k) * 256);

    // per-lane X base: lane L supplies X[row (L&7)][d4 = b*8 + (L>>3)] to the
    // readlane fan-out (rl = t*8+rr  <->  rr=rl&7, d4r=rl>>3). Direct global
    // read; values bit-identical to the old sX path.
    const float* xbase = X + (size_t)(block_row + wg * 8 + (lane & 7)) * DD
                           + (lane >> 3) * 4;

    // row constants (bit-identical to numpy's x2)
    float x2r[RPW];
    #pragma unroll
    for (int rr = 0; rr < RPW; ++rr) x2r[rr] = x2[block_row + wg * RPW + rr];

    __syncthreads();   // drains vmcnt -> both groups' buf0 resident

    float best[RPW];
    int   besti[RPW];
    #pragma unroll
    for (int rr = 0; rr < RPW; ++rr) { best[rr] = 3.4e38f; besti[rr] = 0; }

    for (int ch = 0; ch < NCHG; ++ch) {
        const int chg = g * NCHG + ch;                 // global chunk id
        float c2v[8];
        #pragma unroll
        for (int j = 0; j < 8; ++j) c2v[j] = c2[chg * NT + lane + 64 * j];

        float acc[8][8];
        #pragma unroll
        for (int rr = 0; rr < 8; ++rr)
            #pragma unroll
            for (int j = 0; j < 8; ++j) acc[rr][j] = 0.0f;

        float4 xp;   // current X super-block (reloaded every 8 slices)

        #pragma unroll 8
        for (int sl = 0; sl < NSL; ++sl) {
            const int e = ch * NSL + sl;

            // ---- async-stage next C slice (group-private stream) ----
            if (e + 1 < NEPG) {
                const int nch = (e + 1) >> 6, nsl = (e + 1) & 63;
                const float* so = CBg + (size_t)nch * (NT * DD) + nsl * DT;
                float* dst = sCg + ((e + 1) & 1) * CBUFF;
                #pragma unroll
                for (int k = 0; k < 4; ++k)
                    gl2lds16(so + coff[k], dst + (wgu * 4 + k) * 256);
            }

            // ---- X super-block: one global b128 per 8 slices (L2-hot) ----
            if ((sl & 7) == 0)
                xp = *reinterpret_cast<const float4*>(xbase + (sl >> 3) * 32);

            // ---- compute: 1 d4-step on current buffer ----
            const int t = sl & 7;                     // d4 within super-block
            const float* cb_ = sCg + (e & 1) * CBUFF + lane * 4;
            float4 cc[8];
            #pragma unroll
            for (int j = 0; j < 8; ++j)
                cc[j] = *reinterpret_cast<const float4*>(cb_ + j * 256);
            #pragma unroll
            for (int rr = 0; rr < 8; ++rr) {
                const int rl = t * 8 + rr;            // lane holding X[rr][d4]
                const float sx = rlane(xp.x, rl);
                const float sy = rlane(xp.y, rl);
                const float sz = rlane(xp.z, rl);
                const float sw = rlane(xp.w, rl);
                #pragma unroll
                for (int j = 0; j < 8; ++j) {
                    acc[rr][j] = fmaf(sx, cc[j].x, acc[rr][j]);
                    acc[rr][j] = fmaf(sy, cc[j].y, acc[rr][j]);
                    acc[rr][j] = fmaf(sz, cc[j].z, acc[rr][j]);
                    acc[rr][j] = fmaf(sw, cc[j].w, acc[rr][j]);
                }
            }
            __syncthreads();   // reads of cur buf done; next-slice DMA drained
        }

        // ---- fp32 distance exactly as numpy, then argmin (first-index ties) ----
        #pragma unroll
        for (int rr = 0; rr < 8; ++rr) {
            #pragma unroll
            for (int j = 0; j < 8; ++j) {
                const int col = chg * NT + lane + 64 * j;
                float t1 = x2r[rr] + c2v[j];
                float sc = t1 - 2.0f * acc[rr][j];
                if (sc < best[rr] || (sc == best[rr] && col < besti[rr])) {
                    best[rr] = sc; besti[rr] = col;
                }
            }
        }
    }

    // ---- per-row argmin across the wave's 64 lanes (xor butterfly) ----
    #pragma unroll
    for (int rr = 0; rr < RPW; ++rr) {
        float b = best[rr];
        int  bi = besti[rr];
        #pragma unroll
        for (int m = 32; m > 0; m >>= 1) {
            float b2 = __shfl_xor(b, m, 64);
            int   i2 = __shfl_xor(bi, m, 64);
            if (b2 < b || (b2 == b && i2 < bi)) { b = b2; bi = i2; }
        }
        if (lane == 0) {
            gbest[g][wg * RPW + rr] = b;
            gidx [g][wg * RPW + rr] = bi;
        }
    }
    __syncthreads();

    // ---- cross-group merge: group 0 has lower cols, so tie -> group 0 ----
    if (tid < MT) {
        const float b0 = gbest[0][tid], b1 = gbest[1][tid];
        const int bi = (b1 < b0) ? gidx[1][tid] : gidx[0][tid];
        out[OUT_IDS + block_row + tid] = (float)bi;   // exact integer in float
        atomicAdd(&hist[bi], mask[block_row + tid]);  // mask=1.0 -> order-exact
    }
}

// ---------------------------------------------------------------------------
// Kernel 2b: gather + MSE partials. 512 blocks x 256 threads on the OLD
//   32-row geometry — code is VERBATIM the verified R0 epilogue (same
//   element->thread mapping, same fma chain, same shfl tree, same wsum order)
//   so partial[512] and outq/outst are bit-identical. ids read back from the
//   float ids output (values are exact small integers).
// ---------------------------------------------------------------------------
__global__ __launch_bounds__(256) void vq_gather(const float* __restrict__ X,
                                                 const float* __restrict__ CB,
                                                 float* __restrict__ out,
                                                 float* __restrict__ partial) {
    __shared__ int   row_id[32];
    __shared__ float wsum[4];
    const int tid  = threadIdx.x;
    const int lane = tid & 63;
    const int wid  = tid >> 6;
    const int block_row = blockIdx.x * 32;

    if (tid < 32) row_id[tid] = (int)out[OUT_IDS + block_row + tid];
    __syncthreads();

    float msep = 0.0f;
    float* outq  = out + OUT_Q;
    float* outst = out + OUT_ST;
    #pragma unroll
    for (int i = 0; i < 8; ++i) {
        int g2 = i * 256 + tid;         // 0..2047 covers 32 rows x 64 float4
        int row = g2 >> 6;
        int d4  = g2 & 63;
        int id  = row_id[row];
        float4 q = reinterpret_cast<const float4*>(CB)[(size_t)id * (DD / 4) + d4];
        float4 x = reinterpret_cast<const float4*>(X)[(size_t)(block_row + row) * (DD / 4) + d4];
        float4 st;
        st.x = x.x + (q.x - x.x);
        st.y = x.y + (q.y - x.y);
        st.z = x.z + (q.z - x.z);
        st.w = x.w + (q.w - x.w);
        float dx = x.x - q.x; msep = fmaf(dx, dx, msep);
        dx = x.y - q.y; msep = fmaf(dx, dx, msep);
        dx = x.z - q.z; msep = fmaf(dx, dx, msep);
        dx = x.w - q.w; msep = fmaf(dx, dx, msep);
        size_t o = (size_t)(block_row + row) * (DD / 4) + d4;
        reinterpret_cast<float4*>(outq)[o]  = q;
        reinterpret_cast<float4*>(outst)[o] = st;
    }
    #pragma unroll
    for (int off = 32; off > 0; off >>= 1) msep += __shfl_down(msep, off, 64);
    if (lane == 0) wsum[wid] = msep;
    __syncthreads();
    if (tid == 0) partial[blockIdx.x] = wsum[0] + wsum[1] + wsum[2] + wsum[3];
}

// ---------------------------------------------------------------------------
// Kernel 3: finalize losses + perplexity (double precision, single block)
// ---------------------------------------------------------------------------
__global__ __launch_bounds__(256) void vq_finalize(const float* __restrict__ partial,
                                                   const float* __restrict__ hist,
                                                   float* __restrict__ out) {
    __shared__ double red[256];
    const int tid = threadIdx.x;

    double ps = 0.0;
    for (int j = tid; j < NBLOCKS; j += 256) ps += (double)partial[j];
    red[tid] = ps;
    __syncthreads();
    for (int s = 128; s > 0; s >>= 1) {
        if (tid < s) red[tid] += red[tid + s];
        __syncthreads();
    }
    double mse_sum = red[0];
    __syncthreads();

    double hs = 0.0;
    for (int j = tid; j < KK; j += 256) hs += (double)hist[j];
    red[tid] = hs;
    __syncthreads();
    for (int s = 128; s > 0; s >>= 1) {
        if (tid < s) red[tid] += red[tid + s];
        __syncthreads();
    }
    double denom = red[0] > 1.0 ? red[0] : 1.0;
    __syncthreads();

    double ent = 0.0;
    for (int j = tid; j < KK; j += 256) {
        double p = (double)hist[j] / denom;
        ent += p * log(p + 1e-8);
    }
    red[tid] = ent;
    __syncthreads();
    for (int s = 128; s > 0; s >>= 1) {
        if (tid < s) red[tid] += red[tid + s];
        __syncthreads();
    }

    if (tid == 0) {
        double mse = mse_sum / (double)((size_t)NN * DD);
        out[OUT_COMMIT] = (float)(mse * 0.25);
        out[OUT_CBL]    = (float)mse;
        out[OUT_PERP]   = (float)exp(-red[0]);
    }
}

// ---------------------------------------------------------------------------
extern "C" void kernel_launch(void* const* d_in, const int* in_sizes, int n_in,
                              void* d_out, int out_size, void* d_ws, size_t ws_size,
                              hipStream_t stream) {
    const float* latents = (const float*)d_in[0];   // [16,1024,256]
    const float* mask    = (const float*)d_in[1];   // [16,1024]
    const float* cb      = (const float*)d_in[2];   // [8192,256]
    float* out = (float*)d_out;

    // workspace layout (floats): hist[8192] | partial[512] | c2[8192] | x2[16384]
    float* hist    = (float*)d_ws;
    float* partial = hist + KK;
    float* c2      = partial + NBLOCKS;
    float* x2      = c2 + KK;

    hipMemsetAsync(d_ws, 0, KK * sizeof(float), stream);   // zero histogram
    rowsumsq<<<KK / 64, 256, 0, stream>>>(cb, c2);          // numpy-exact |c|^2
    rowsumsq<<<NN / 64, 256, 0, stream>>>(latents, x2);     // numpy-exact |x|^2
    vq_main<<<NBM, 256, 0, stream>>>(latents, cb, c2, x2, mask, out, hist);
    vq_gather<<<NBLOCKS, 256, 0, stream>>>(latents, cb, out, partial);
    vq_finalize<<<1, 256, 0, stream>>>(partial, hist, out);
}

// Round 5
// 2068.410 us; speedup vs baseline: 1.2215x; 1.2215x over previous
//
#include <hip/hip_runtime.h>
#include <math.h>

// Problem constants
#define DD 256            // latent dim
#define KK 8192           // codebook size
#define NN 16384          // rows
#define MT 16             // rows per block (main kernel; 2 row-groups x 8)
#define RPW 8             // rows per wave (keeps fma:overhead ratio)
#define NT 512            // codebook cols per chunk (lane + 64*j, j 0..7)
#define NCHG 8            // chunks per group (16 total / 2 groups)
#define DT 4              // d-slice floats per epoch (1 d4-step)
#define NSL (DD / DT)     // 64 slices per chunk
#define NEPG (NCHG * NSL) // 512 epochs per group
#define NBM (NN / MT)     // 1024 main blocks x 256 thr -> 4 blocks/CU, zero tail
#define NBLOCKS 512       // gather/partial blocks (old verified 32-row geometry)
#define CBUFF 2048        // floats per C buffer (512 cols x 4 d) = 8 KB
#define RSTRIDE 260       // rowsumsq staging stride (unchanged, verified)

// Output layout (all float32, concatenated in reference return order)
#define OUT_IDS   0
#define OUT_Q     16384
#define OUT_ST    4210688          // 16384 + 4194304
#define OUT_COMMIT 8404992
#define OUT_CBL    8404993
#define OUT_PERP   8404994

// ---------------------------------------------------------------------------
// async global->LDS DMA: lane i's 16B lands at ldsbase + i*16 (contiguous 1KB).
// Global source address is PER-LANE -> layout shuffles live on the source side.
// ---------------------------------------------------------------------------
__device__ __forceinline__ void gl2lds16(const float* g, float* l) {
    __builtin_amdgcn_global_load_lds(
        (const __attribute__((address_space(1))) float*)g,
        (__attribute__((address_space(3))) float*)l, 16, 0, 0);
}

// readlane: pull a float from a given lane into an SGPR (uniform). Bit-exact.
__device__ __forceinline__ float rlane(float v, int l) {
    return __int_as_float(__builtin_amdgcn_readlane(__float_as_int(v), l));
}

// ---------------------------------------------------------------------------
// numpy pairwise-sum replica for sum of squares (verified bit-exact)
// ---------------------------------------------------------------------------
__device__ __forceinline__ float np_block128_sumsq(const float* p) {
    #pragma clang fp contract(off)
    float r0 = p[0] * p[0], r1 = p[1] * p[1], r2 = p[2] * p[2], r3 = p[3] * p[3];
    float r4 = p[4] * p[4], r5 = p[5] * p[5], r6 = p[6] * p[6], r7 = p[7] * p[7];
    for (int i = 8; i < 128; i += 8) {
        r0 = r0 + p[i + 0] * p[i + 0];
        r1 = r1 + p[i + 1] * p[i + 1];
        r2 = r2 + p[i + 2] * p[i + 2];
        r3 = r3 + p[i + 3] * p[i + 3];
        r4 = r4 + p[i + 4] * p[i + 4];
        r5 = r5 + p[i + 5] * p[i + 5];
        r6 = r6 + p[i + 6] * p[i + 6];
        r7 = r7 + p[i + 7] * p[i + 7];
    }
    return ((r0 + r1) + (r2 + r3)) + ((r4 + r5) + (r6 + r7));
}

__device__ __forceinline__ float np_pairwise256_sumsq(const float* a) {
    #pragma clang fp contract(off)
    float s0 = np_block128_sumsq(a);
    float s1 = np_block128_sumsq(a + 128);
    return s0 + s1;
}

// ---------------------------------------------------------------------------
// Kernel 1: per-row sum of squares, numpy-pairwise-exact (unchanged, verified)
// ---------------------------------------------------------------------------
__global__ __launch_bounds__(256) void rowsumsq(const float* __restrict__ A,
                                                float* __restrict__ out) {
    __shared__ __align__(16) float sA[64][RSTRIDE];
    const int tid = threadIdx.x;
    const int base = blockIdx.x * 64;
    #pragma unroll
    for (int i = 0; i < 16; ++i) {
        int g = i * 256 + tid;
        int row = g >> 6, d4 = g & 63;
        float4 v = reinterpret_cast<const float4*>(A)[(size_t)(base + row) * (DD / 4) + d4];
        *reinterpret_cast<float4*>(&sA[row][d4 * 4]) = v;
    }
    __syncthreads();
    if (tid < 64) out[base + tid] = np_pairwise256_sumsq(sA[tid]);
}

// ---------------------------------------------------------------------------
// Kernel 2: main VQ distance+argmin kernel. 1024 blocks x 256 threads (4 waves).
//   ROUND-5 FIX (one integer vs R4): launch_bounds (256,4) -> (256,2).
//   Empirical hipcc law from R0/R1/R3/R4 counters: VGPR cap = 256/arg2
//   REGARDLESS of block size. arg2=4 -> 64-VGPR cap -> acc[8][8] spilled
//   (R1 AND R4: FETCH 0.65/2.2 GB scratch traffic). arg2=2 -> cap 128;
//   this loop naturally uses ~100-108 (R0/R3) -> no spill.
//   Residency: this geometry admits 4 blocks/CU from raw resources
//   (LDS 4 x 33280 = 133 KB <= 160 KB; VGPR 4 waves/EU x ~104 = 416 <= 512),
//   and even the pessimistic "<= 2*arg2 waves/EU" reading of the R0-R4
//   table allows 4 waves/EU = 16 waves/CU. Target: 16 waves/CU, no spill.
//   Structure (unchanged from R4, verified absmax 0.0):
//   - MT=16 rows (2 row-groups x 8), K-split 2-way (2 chunk-groups x 2 waves).
//   - No sX stage: xp float4 read directly from global X once per 8 epochs
//     (16 KB X block, L1/L2-hot after chunk 0; latency hidden by TLP).
//   - C stream: per group, double-buffered 8 KB slices (DT=4), gl2lds DMA,
//     1 barrier/epoch (same verified sync structure as R0/R3/R4).
//   - gather/MSE epilogue in vq_gather (old 512-block geometry, bit-exact).
//   Per-(row,col) fp32 fma chain (d = 0..255, x/y/z/w order) unchanged ->
//   scores bit-exact; argmin first-index ties preserved (ascending chunks per
//   group; cross-group merge strict-less favors group 0 = lower cols).
// ---------------------------------------------------------------------------
__global__ __launch_bounds__(256, 2) void vq_main(const float* __restrict__ X,
                                                  const float* __restrict__ CB,
                                                  const float* __restrict__ c2,
                                                  const float* __restrict__ x2,
                                                  const float* __restrict__ mask,
                                                  float* __restrict__ out,
                                                  float* __restrict__ hist) {
    __shared__ __align__(16) float sC[4 * CBUFF];   // 32 KB: 2 groups x dbuf x 8 KB
    __shared__ float gbest[2][MT];
    __shared__ int   gidx[2][MT];

    const int tid  = threadIdx.x;
    const int lane = tid & 63;
    const int wid  = tid >> 6;                                  // 0..3
    const int widu = __builtin_amdgcn_readfirstlane(wid);       // uniform copy
    const int g    = wid >> 1;        // chunk-group (0: cols 0..4095, 1: 4096..8191)
    const int gu   = widu >> 1;
    const int wg   = wid & 1;         // row-group within block (8 rows each)
    const int wgu  = widu & 1;
    const int block_row = blockIdx.x * MT;

    // ---- C staging source offsets: unit u = col (single d4-plane).
    //      Group's 8 KB/epoch staged by its 2 waves -> 4 calls/wave.
    unsigned coff[4];
    #pragma unroll
    for (int k = 0; k < 4; ++k)
        coff[k] = ((wgu * 4u + (unsigned)k) * 64u + (unsigned)lane) * DD;

    const float* CBg = CB + (size_t)gu * NCHG * NT * DD;   // group's chunk base
    float* sCg = &sC[gu * 2 * CBUFF];                      // group's buffer pair
    #pragma unroll
    for (int k = 0; k < 4; ++k)     // epoch 0 (group chunk 0, sl 0) -> buf 0
        gl2lds16(CBg + coff[k], sCg + (wgu * 4 + k) * 256);

    // per-lane X base: lane L supplies X[row (L&7)][d4 = b*8 + (L>>3)] to the
    // readlane fan-out (rl = t*8+rr  <->  rr=rl&7, d4r=rl>>3). Direct global
    // read; values bit-identical to the old sX path.
    const float* xbase = X + (size_t)(block_row + wg * 8 + (lane & 7)) * DD
                           + (lane >> 3) * 4;

    // row constants (bit-identical to numpy's x2)
    float x2r[RPW];
    #pragma unroll
    for (int rr = 0; rr < RPW; ++rr) x2r[rr] = x2[block_row + wg * RPW + rr];

    __syncthreads();   // drains vmcnt -> both groups' buf0 resident

    float best[RPW];
    int   besti[RPW];
    #pragma unroll
    for (int rr = 0; rr < RPW; ++rr) { best[rr] = 3.4e38f; besti[rr] = 0; }

    for (int ch = 0; ch < NCHG; ++ch) {
        const int chg = g * NCHG + ch;                 // global chunk id
        float c2v[8];
        #pragma unroll
        for (int j = 0; j < 8; ++j) c2v[j] = c2[chg * NT + lane + 64 * j];

        float acc[8][8];
        #pragma unroll
        for (int rr = 0; rr < 8; ++rr)
            #pragma unroll
            for (int j = 0; j < 8; ++j) acc[rr][j] = 0.0f;

        float4 xp;   // current X super-block (reloaded every 8 slices)

        #pragma unroll 8
        for (int sl = 0; sl < NSL; ++sl) {
            const int e = ch * NSL + sl;

            // ---- async-stage next C slice (group-private stream) ----
            if (e + 1 < NEPG) {
                const int nch = (e + 1) >> 6, nsl = (e + 1) & 63;
                const float* so = CBg + (size_t)nch * (NT * DD) + nsl * DT;
                float* dst = sCg + ((e + 1) & 1) * CBUFF;
                #pragma unroll
                for (int k = 0; k < 4; ++k)
                    gl2lds16(so + coff[k], dst + (wgu * 4 + k) * 256);
            }

            // ---- X super-block: one global b128 per 8 slices (L2-hot) ----
            if ((sl & 7) == 0)
                xp = *reinterpret_cast<const float4*>(xbase + (sl >> 3) * 32);

            // ---- compute: 1 d4-step on current buffer ----
            const int t = sl & 7;                     // d4 within super-block
            const float* cb_ = sCg + (e & 1) * CBUFF + lane * 4;
            float4 cc[8];
            #pragma unroll
            for (int j = 0; j < 8; ++j)
                cc[j] = *reinterpret_cast<const float4*>(cb_ + j * 256);
            #pragma unroll
            for (int rr = 0; rr < 8; ++rr) {
                const int rl = t * 8 + rr;            // lane holding X[rr][d4]
                const float sx = rlane(xp.x, rl);
                const float sy = rlane(xp.y, rl);
                const float sz = rlane(xp.z, rl);
                const float sw = rlane(xp.w, rl);
                #pragma unroll
                for (int j = 0; j < 8; ++j) {
                    acc[rr][j] = fmaf(sx, cc[j].x, acc[rr][j]);
                    acc[rr][j] = fmaf(sy, cc[j].y, acc[rr][j]);
                    acc[rr][j] = fmaf(sz, cc[j].z, acc[rr][j]);
                    acc[rr][j] = fmaf(sw, cc[j].w, acc[rr][j]);
                }
            }
            __syncthreads();   // reads of cur buf done; next-slice DMA drained
        }

        // ---- fp32 distance exactly as numpy, then argmin (first-index ties) ----
        #pragma unroll
        for (int rr = 0; rr < 8; ++rr) {
            #pragma unroll
            for (int j = 0; j < 8; ++j) {
                const int col = chg * NT + lane + 64 * j;
                float t1 = x2r[rr] + c2v[j];
                float sc = t1 - 2.0f * acc[rr][j];
                if (sc < best[rr] || (sc == best[rr] && col < besti[rr])) {
                    best[rr] = sc; besti[rr] = col;
                }
            }
        }
    }

    // ---- per-row argmin across the wave's 64 lanes (xor butterfly) ----
    #pragma unroll
    for (int rr = 0; rr < RPW; ++rr) {
        float b = best[rr];
        int  bi = besti[rr];
        #pragma unroll
        for (int m = 32; m > 0; m >>= 1) {
            float b2 = __shfl_xor(b, m, 64);
            int   i2 = __shfl_xor(bi, m, 64);
            if (b2 < b || (b2 == b && i2 < bi)) { b = b2; bi = i2; }
        }
        if (lane == 0) {
            gbest[g][wg * RPW + rr] = b;
            gidx [g][wg * RPW + rr] = bi;
        }
    }
    __syncthreads();

    // ---- cross-group merge: group 0 has lower cols, so tie -> group 0 ----
    if (tid < MT) {
        const float b0 = gbest[0][tid], b1 = gbest[1][tid];
        const int bi = (b1 < b0) ? gidx[1][tid] : gidx[0][tid];
        out[OUT_IDS + block_row + tid] = (float)bi;   // exact integer in float
        atomicAdd(&hist[bi], mask[block_row + tid]);  // mask=1.0 -> order-exact
    }
}

// ---------------------------------------------------------------------------
// Kernel 2b: gather + MSE partials. 512 blocks x 256 threads on the OLD
//   32-row geometry — code is VERBATIM the verified R0 epilogue (same
//   element->thread mapping, same fma chain, same shfl tree, same wsum order)
//   so partial[512] and outq/outst are bit-identical. ids read back from the
//   float ids output (values are exact small integers).
// ---------------------------------------------------------------------------
__global__ __launch_bounds__(256) void vq_gather(const float* __restrict__ X,
                                                 const float* __restrict__ CB,
                                                 float* __restrict__ out,
                                                 float* __restrict__ partial) {
    __shared__ int   row_id[32];
    __shared__ float wsum[4];
    const int tid  = threadIdx.x;
    const int lane = tid & 63;
    const int wid  = tid >> 6;
    const int block_row = blockIdx.x * 32;

    if (tid < 32) row_id[tid] = (int)out[OUT_IDS + block_row + tid];
    __syncthreads();

    float msep = 0.0f;
    float* outq  = out + OUT_Q;
    float* outst = out + OUT_ST;
    #pragma unroll
    for (int i = 0; i < 8; ++i) {
        int g2 = i * 256 + tid;         // 0..2047 covers 32 rows x 64 float4
        int row = g2 >> 6;
        int d4  = g2 & 63;
        int id  = row_id[row];
        float4 q = reinterpret_cast<const float4*>(CB)[(size_t)id * (DD / 4) + d4];
        float4 x = reinterpret_cast<const float4*>(X)[(size_t)(block_row + row) * (DD / 4) + d4];
        float4 st;
        st.x = x.x + (q.x - x.x);
        st.y = x.y + (q.y - x.y);
        st.z = x.z + (q.z - x.z);
        st.w = x.w + (q.w - x.w);
        float dx = x.x - q.x; msep = fmaf(dx, dx, msep);
        dx = x.y - q.y; msep = fmaf(dx, dx, msep);
        dx = x.z - q.z; msep = fmaf(dx, dx, msep);
        dx = x.w - q.w; msep = fmaf(dx, dx, msep);
        size_t o = (size_t)(block_row + row) * (DD / 4) + d4;
        reinterpret_cast<float4*>(outq)[o]  = q;
        reinterpret_cast<float4*>(outst)[o] = st;
    }
    #pragma unroll
    for (int off = 32; off > 0; off >>= 1) msep += __shfl_down(msep, off, 64);
    if (lane == 0) wsum[wid] = msep;
    __syncthreads();
    if (tid == 0) partial[blockIdx.x] = wsum[0] + wsum[1] + wsum[2] + wsum[3];
}

// ---------------------------------------------------------------------------
// Kernel 3: finalize losses + perplexity (double precision, single block)
// ---------------------------------------------------------------------------
__global__ __launch_bounds__(256) void vq_finalize(const float* __restrict__ partial,
                                                   const float* __restrict__ hist,
                                                   float* __restrict__ out) {
    __shared__ double red[256];
    const int tid = threadIdx.x;

    double ps = 0.0;
    for (int j = tid; j < NBLOCKS; j += 256) ps += (double)partial[j];
    red[tid] = ps;
    __syncthreads();
    for (int s = 128; s > 0; s >>= 1) {
        if (tid < s) red[tid] += red[tid + s];
        __syncthreads();
    }
    double mse_sum = red[0];
    __syncthreads();

    double hs = 0.0;
    for (int j = tid; j < KK; j += 256) hs += (double)hist[j];
    red[tid] = hs;
    __syncthreads();
    for (int s = 128; s > 0; s >>= 1) {
        if (tid < s) red[tid] += red[tid + s];
        __syncthreads();
    }
    double denom = red[0] > 1.0 ? red[0] : 1.0;
    __syncthreads();

    double ent = 0.0;
    for (int j = tid; j < KK; j += 256) {
        double p = (double)hist[j] / denom;
        ent += p * log(p + 1e-8);
    }
    red[tid] = ent;
    __syncthreads();
    for (int s = 128; s > 0; s >>= 1) {
        if (tid < s) red[tid] += red[tid + s];
        __syncthreads();
    }

    if (tid == 0) {
        double mse = mse_sum / (double)((size_t)NN * DD);
        out[OUT_COMMIT] = (float)(mse * 0.25);
        out[OUT_CBL]    = (float)mse;
        out[OUT_PERP]   = (float)exp(-red[0]);
    }
}

// ---------------------------------------------------------------------------
extern "C" void kernel_launch(void* const* d_in, const int* in_sizes, int n_in,
                              void* d_out, int out_size, void* d_ws, size_t ws_size,
                              hipStream_t stream) {
    const float* latents = (const float*)d_in[0];   // [16,1024,256]
    const float* mask    = (const float*)d_in[1];   // [16,1024]
    const float* cb      = (const float*)d_in[2];   // [8192,256]
    float* out = (float*)d_out;

    // workspace layout (floats): hist[8192] | partial[512] | c2[8192] | x2[16384]
    float* hist    = (float*)d_ws;
    float* partial = hist + KK;
    float* c2      = partial + NBLOCKS;
    float* x2      = c2 + KK;

    hipMemsetAsync(d_ws, 0, KK * sizeof(float), stream);   // zero histogram
    rowsumsq<<<KK / 64, 256, 0, stream>>>(cb, c2);          // numpy-exact |c|^2
    rowsumsq<<<NN / 64, 256, 0, stream>>>(latents, x2);     // numpy-exact |x|^2
    vq_main<<<NBM, 256, 0, stream>>>(latents, cb, c2, x2, mask, out, hist);
    vq_gather<<<NBLOCKS, 256, 0, stream>>>(latents, cb, out, partial);
    vq_finalize<<<1, 256, 0, stream>>>(partial, hist, out);
}

// Round 6
// 941.430 us; speedup vs baseline: 2.6838x; 2.1971x over previous
//
#include <hip/hip_runtime.h>
#include <math.h>

// Problem constants
#define DD 256            // latent dim
#define KK 8192           // codebook size
#define NN 16384          // rows
#define MT 32             // rows per block (4 waves x 8 rows, R0 ownership)
#define RPW 8             // rows per wave
#define NCH 16            // chunks of 512 cols
#define NT 512            // cols per chunk (lane + 64*j, j 0..7)
#define NBLOCKS 512       // main + gather grid (R0 geometry)
#define RSTRIDE 260       // rowsumsq staging stride (unchanged, verified)

// Output layout (all float32, concatenated in reference return order)
#define OUT_IDS   0
#define OUT_Q     16384
#define OUT_ST    4210688          // 16384 + 4194304
#define OUT_COMMIT 8404992
#define OUT_CBL    8404993
#define OUT_PERP   8404994

// readlane: pull a float from a given lane into an SGPR (uniform). Bit-exact.
__device__ __forceinline__ float rlane(float v, int l) {
    return __int_as_float(__builtin_amdgcn_readlane(__float_as_int(v), l));
}

// ---------------------------------------------------------------------------
// numpy pairwise-sum replica for sum of squares (verified bit-exact)
// ---------------------------------------------------------------------------
__device__ __forceinline__ float np_block128_sumsq(const float* p) {
    #pragma clang fp contract(off)
    float r0 = p[0] * p[0], r1 = p[1] * p[1], r2 = p[2] * p[2], r3 = p[3] * p[3];
    float r4 = p[4] * p[4], r5 = p[5] * p[5], r6 = p[6] * p[6], r7 = p[7] * p[7];
    for (int i = 8; i < 128; i += 8) {
        r0 = r0 + p[i + 0] * p[i + 0];
        r1 = r1 + p[i + 1] * p[i + 1];
        r2 = r2 + p[i + 2] * p[i + 2];
        r3 = r3 + p[i + 3] * p[i + 3];
        r4 = r4 + p[i + 4] * p[i + 4];
        r5 = r5 + p[i + 5] * p[i + 5];
        r6 = r6 + p[i + 6] * p[i + 6];
        r7 = r7 + p[i + 7] * p[i + 7];
    }
    return ((r0 + r1) + (r2 + r3)) + ((r4 + r5) + (r6 + r7));
}

__device__ __forceinline__ float np_pairwise256_sumsq(const float* a) {
    #pragma clang fp contract(off)
    float s0 = np_block128_sumsq(a);
    float s1 = np_block128_sumsq(a + 128);
    return s0 + s1;
}

// ---------------------------------------------------------------------------
// Kernel 1: per-row sum of squares, numpy-pairwise-exact (unchanged, verified)
// ---------------------------------------------------------------------------
__global__ __launch_bounds__(256) void rowsumsq(const float* __restrict__ A,
                                                float* __restrict__ out) {
    __shared__ __align__(16) float sA[64][RSTRIDE];
    const int tid = threadIdx.x;
    const int base = blockIdx.x * 64;
    #pragma unroll
    for (int i = 0; i < 16; ++i) {
        int g = i * 256 + tid;
        int row = g >> 6, d4 = g & 63;
        float4 v = reinterpret_cast<const float4*>(A)[(size_t)(base + row) * (DD / 4) + d4];
        *reinterpret_cast<float4*>(&sA[row][d4 * 4]) = v;
    }
    __syncthreads();
    if (tid < 64) out[base + tid] = np_pairwise256_sumsq(sA[tid]);
}

// ---------------------------------------------------------------------------
// Kernel 1b: codebook transpose into d4-plane-major layout.
//   CBt[p*8192 + col] (float4) = CB[col][4p .. 4p+3]   (p = 0..63)
//   Bit-exact copy. Makes the main kernel's per-lane codebook reads
//   (col = base + lane) perfectly coalesced 16B/lane -> 1KB/instr.
//   CBt lives in out+OUT_Q scratch (2M float4 <= 4.19M floats available);
//   vq_gather overwrites every element of that region afterwards.
// ---------------------------------------------------------------------------
__global__ __launch_bounds__(256) void cb_transpose(const float* __restrict__ CB,
                                                    float4* __restrict__ CBt) {
    const int id = blockIdx.x * 256 + threadIdx.x;   // 0 .. 64*8192-1
    const int p   = id >> 13;
    const int col = id & (KK - 1);
    CBt[id] = *reinterpret_cast<const float4*>(CB + (size_t)col * DD + p * 4);
}

// ---------------------------------------------------------------------------
// Kernel 2: main VQ distance+argmin kernel — BARRIER-FREE register streaming.
//   ROUND-6 RESTRUCTURE. Five rounds pinned the hipcc law: launch_bounds
//   arg2 = resident waves/SIMD AND VGPR cap = 256/arg2 -> with a 64-reg
//   accumulator, >2 waves/SIMD is unreachable without spill. So instead of
//   chasing occupancy, remove the stall: the per-epoch __syncthreads (full
//   vmcnt drain x512) existed only because raw codebook reads were
//   1KB-strided. With CBt (plane-major) the reads are coalesced, so C
//   streams straight into REGISTERS: no LDS staging, no DMA, NO BARRIERS
//   in the hot loop. Compiler software-pipelines loads across fma blocks
//   (nothing blocks code motion); 2 waves/SIMD ILP covers L1/L2 latency
//   (~120-300cy << 512cy fma per step). L2 demand ~16GB/600us = 3.3 TB/s
//   per XCD < 4.3 ceiling even with zero L1 sharing.
//   Ownership = verified R0 semantics: 512 blocks x 4 waves, wave = 8 rows
//   x ALL 8192 cols (no cross-group merge). Per-(row,col) fp32 fma chain
//   d=0..255 in x/y/z/w order, score fl(fl(x2+c2)-2m), first-index ties,
//   butterfly argmin — all byte-identical to verified R0/R5 code paths.
//   X read direct from global (R5-verified mapping, L1-resident).
//   No launch_bounds arg2 -> regalloc free (grid-limited to 8 waves/CU
//   anyway; up to 256 VGPR available at 2 waves/SIMD, no spill expected).
// ---------------------------------------------------------------------------
__global__ __launch_bounds__(256) void vq_main(const float* __restrict__ X,
                                               const float4* __restrict__ CBt,
                                               const float* __restrict__ c2,
                                               const float* __restrict__ x2,
                                               const float* __restrict__ mask,
                                               float* __restrict__ out,
                                               float* __restrict__ hist) {
    __shared__ int row_id[MT];

    const int tid  = threadIdx.x;
    const int lane = tid & 63;
    const int wid  = tid >> 6;                // 0..3, wave owns rows wid*8..+7
    const int block_row = blockIdx.x * MT;

    // per-lane X base: lane L supplies X[row (L&7)][d4 = b*8 + (L>>3)] to the
    // readlane fan-out (rl = t*8+rr <-> rr=rl&7, t=rl>>3). R5-verified.
    const float* xbase = X + (size_t)(block_row + wid * RPW + (lane & 7)) * DD
                           + (lane >> 3) * 4;

    // row constants (bit-identical to numpy's x2)
    float x2r[RPW];
    #pragma unroll
    for (int rr = 0; rr < RPW; ++rr) x2r[rr] = x2[block_row + wid * RPW + rr];

    float best[RPW];
    int   besti[RPW];
    #pragma unroll
    for (int rr = 0; rr < RPW; ++rr) { best[rr] = 3.4e38f; besti[rr] = 0; }

    const float4* cbt_lane = CBt + lane;      // per-lane column offset

    for (int ch = 0; ch < NCH; ++ch) {
        float c2v[8];
        #pragma unroll
        for (int j = 0; j < 8; ++j) c2v[j] = c2[ch * NT + lane + 64 * j];

        float acc[8][8];
        #pragma unroll
        for (int rr = 0; rr < 8; ++rr)
            #pragma unroll
            for (int j = 0; j < 8; ++j) acc[rr][j] = 0.0f;

        const float4* cbase = cbt_lane + ch * NT;   // plane 0 of this chunk

        for (int b = 0; b < 8; ++b) {               // d4 super-blocks
            const float4 xp = *reinterpret_cast<const float4*>(xbase + b * 32);
            #pragma unroll
            for (int t = 0; t < 8; ++t) {
                const int p = b * 8 + t;            // d4 plane index 0..63
                const float4* src = cbase + (size_t)p * KK;
                float4 cc[8];
                #pragma unroll
                for (int j = 0; j < 8; ++j) cc[j] = src[64 * j];   // coalesced
                #pragma unroll
                for (int rr = 0; rr < 8; ++rr) {
                    const int rl = t * 8 + rr;      // lane holding X[rr][p]
                    const float sx = rlane(xp.x, rl);
                    const float sy = rlane(xp.y, rl);
                    const float sz = rlane(xp.z, rl);
                    const float sw = rlane(xp.w, rl);
                    #pragma unroll
                    for (int j = 0; j < 8; ++j) {
                        acc[rr][j] = fmaf(sx, cc[j].x, acc[rr][j]);
                        acc[rr][j] = fmaf(sy, cc[j].y, acc[rr][j]);
                        acc[rr][j] = fmaf(sz, cc[j].z, acc[rr][j]);
                        acc[rr][j] = fmaf(sw, cc[j].w, acc[rr][j]);
                    }
                }
            }
        }

        // ---- fp32 distance exactly as numpy, then argmin (first-index ties) ----
        #pragma unroll
        for (int rr = 0; rr < 8; ++rr) {
            #pragma unroll
            for (int j = 0; j < 8; ++j) {
                const int col = ch * NT + lane + 64 * j;
                float t1 = x2r[rr] + c2v[j];
                float sc = t1 - 2.0f * acc[rr][j];
                if (sc < best[rr] || (sc == best[rr] && col < besti[rr])) {
                    best[rr] = sc; besti[rr] = col;
                }
            }
        }
    }

    // ---- per-row argmin across the wave's 64 lanes (xor butterfly) ----
    #pragma unroll
    for (int rr = 0; rr < RPW; ++rr) {
        float b = best[rr];
        int  bi = besti[rr];
        #pragma unroll
        for (int m = 32; m > 0; m >>= 1) {
            float b2 = __shfl_xor(b, m, 64);
            int   i2 = __shfl_xor(bi, m, 64);
            if (b2 < b || (b2 == b && i2 < bi)) { b = b2; bi = i2; }
        }
        if (lane == 0) row_id[wid * RPW + rr] = bi;
    }
    __syncthreads();   // the ONLY block-wide barrier in this kernel

    if (tid < MT) {
        int bi = row_id[tid];
        out[OUT_IDS + block_row + tid] = (float)bi;   // exact integer in float
        atomicAdd(&hist[bi], mask[block_row + tid]);  // mask=1.0 -> order-exact
    }
}

// ---------------------------------------------------------------------------
// Kernel 2b: gather + MSE partials. 512 blocks x 256 threads, VERBATIM the
//   verified R0 epilogue (same element->thread mapping, fma chain, shfl tree,
//   wsum order) -> partial[512] and outq/outst bit-identical. Overwrites the
//   CBt scratch region entirely (every OUT_Q/OUT_ST element written).
// ---------------------------------------------------------------------------
__global__ __launch_bounds__(256) void vq_gather(const float* __restrict__ X,
                                                 const float* __restrict__ CB,
                                                 float* __restrict__ out,
                                                 float* __restrict__ partial) {
    __shared__ int   row_id[32];
    __shared__ float wsum[4];
    const int tid  = threadIdx.x;
    const int lane = tid & 63;
    const int wid  = tid >> 6;
    const int block_row = blockIdx.x * 32;

    if (tid < 32) row_id[tid] = (int)out[OUT_IDS + block_row + tid];
    __syncthreads();

    float msep = 0.0f;
    float* outq  = out + OUT_Q;
    float* outst = out + OUT_ST;
    #pragma unroll
    for (int i = 0; i < 8; ++i) {
        int g2 = i * 256 + tid;         // 0..2047 covers 32 rows x 64 float4
        int row = g2 >> 6;
        int d4  = g2 & 63;
        int id  = row_id[row];
        float4 q = reinterpret_cast<const float4*>(CB)[(size_t)id * (DD / 4) + d4];
        float4 x = reinterpret_cast<const float4*>(X)[(size_t)(block_row + row) * (DD / 4) + d4];
        float4 st;
        st.x = x.x + (q.x - x.x);
        st.y = x.y + (q.y - x.y);
        st.z = x.z + (q.z - x.z);
        st.w = x.w + (q.w - x.w);
        float dx = x.x - q.x; msep = fmaf(dx, dx, msep);
        dx = x.y - q.y; msep = fmaf(dx, dx, msep);
        dx = x.z - q.z; msep = fmaf(dx, dx, msep);
        dx = x.w - q.w; msep = fmaf(dx, dx, msep);
        size_t o = (size_t)(block_row + row) * (DD / 4) + d4;
        reinterpret_cast<float4*>(outq)[o]  = q;
        reinterpret_cast<float4*>(outst)[o] = st;
    }
    #pragma unroll
    for (int off = 32; off > 0; off >>= 1) msep += __shfl_down(msep, off, 64);
    if (lane == 0) wsum[wid] = msep;
    __syncthreads();
    if (tid == 0) partial[blockIdx.x] = wsum[0] + wsum[1] + wsum[2] + wsum[3];
}

// ---------------------------------------------------------------------------
// Kernel 3: finalize losses + perplexity (double precision, single block)
// ---------------------------------------------------------------------------
__global__ __launch_bounds__(256) void vq_finalize(const float* __restrict__ partial,
                                                   const float* __restrict__ hist,
                                                   float* __restrict__ out) {
    __shared__ double red[256];
    const int tid = threadIdx.x;

    double ps = 0.0;
    for (int j = tid; j < NBLOCKS; j += 256) ps += (double)partial[j];
    red[tid] = ps;
    __syncthreads();
    for (int s = 128; s > 0; s >>= 1) {
        if (tid < s) red[tid] += red[tid + s];
        __syncthreads();
    }
    double mse_sum = red[0];
    __syncthreads();

    double hs = 0.0;
    for (int j = tid; j < KK; j += 256) hs += (double)hist[j];
    red[tid] = hs;
    __syncthreads();
    for (int s = 128; s > 0; s >>= 1) {
        if (tid < s) red[tid] += red[tid + s];
        __syncthreads();
    }
    double denom = red[0] > 1.0 ? red[0] : 1.0;
    __syncthreads();

    double ent = 0.0;
    for (int j = tid; j < KK; j += 256) {
        double p = (double)hist[j] / denom;
        ent += p * log(p + 1e-8);
    }
    red[tid] = ent;
    __syncthreads();
    for (int s = 128; s > 0; s >>= 1) {
        if (tid < s) red[tid] += red[tid + s];
        __syncthreads();
    }

    if (tid == 0) {
        double mse = mse_sum / (double)((size_t)NN * DD);
        out[OUT_COMMIT] = (float)(mse * 0.25);
        out[OUT_CBL]    = (float)mse;
        out[OUT_PERP]   = (float)exp(-red[0]);
    }
}

// ---------------------------------------------------------------------------
extern "C" void kernel_launch(void* const* d_in, const int* in_sizes, int n_in,
                              void* d_out, int out_size, void* d_ws, size_t ws_size,
                              hipStream_t stream) {
    const float* latents = (const float*)d_in[0];   // [16,1024,256]
    const float* mask    = (const float*)d_in[1];   // [16,1024]
    const float* cb      = (const float*)d_in[2];   // [8192,256]
    float* out = (float*)d_out;

    // workspace layout (floats): hist[8192] | partial[512] | c2[8192] | x2[16384]
    float* hist    = (float*)d_ws;
    float* partial = hist + KK;
    float* c2      = partial + NBLOCKS;
    float* x2      = c2 + KK;

    // transposed-codebook scratch lives in the out buffer's OUT_Q region
    // (2M float4 = 8MB <= 16.8MB region); vq_gather later overwrites all of it.
    float4* cbt = reinterpret_cast<float4*>(out + OUT_Q);

    hipMemsetAsync(d_ws, 0, KK * sizeof(float), stream);    // zero histogram
    rowsumsq<<<KK / 64, 256, 0, stream>>>(cb, c2);           // numpy-exact |c|^2
    rowsumsq<<<NN / 64, 256, 0, stream>>>(latents, x2);      // numpy-exact |x|^2
    cb_transpose<<<(64 * KK) / 256, 256, 0, stream>>>(cb, cbt);
    vq_main<<<NBLOCKS, 256, 0, stream>>>(latents, cbt, c2, x2, mask, out, hist);
    vq_gather<<<NBLOCKS, 256, 0, stream>>>(latents, cb, out, partial);
    vq_finalize<<<1, 256, 0, stream>>>(partial, hist, out);
}

// Round 7
// 934.148 us; speedup vs baseline: 2.7047x; 1.0078x over previous
//
#include <hip/hip_runtime.h>
#include <math.h>

// Problem constants
#define DD 256            // latent dim
#define KK 8192           // codebook size
#define NN 16384          // rows
#define MT 16             // rows per block (2 row-groups x 8, K-split 2-way)
#define RPW 8             // rows per wave
#define NT 512            // cols per chunk (lane + 64*j, j 0..7)
#define NCHG 8            // chunks per col-group (16 total / 2 groups)
#define NBM (NN / MT)     // 1024 main blocks x 256 thr -> 16 waves/CU possible
#define NBLOCKS 512       // gather/partial grid (verified 32-row geometry)
#define RSTRIDE 260       // rowsumsq staging stride (unchanged, verified)

// Output layout (all float32, concatenated in reference return order)
#define OUT_IDS   0
#define OUT_Q     16384
#define OUT_ST    4210688          // 16384 + 4194304
#define OUT_COMMIT 8404992
#define OUT_CBL    8404993
#define OUT_PERP   8404994

// ---------------------------------------------------------------------------
// numpy pairwise-sum replica for sum of squares (verified bit-exact)
// ---------------------------------------------------------------------------
__device__ __forceinline__ float np_block128_sumsq(const float* p) {
    #pragma clang fp contract(off)
    float r0 = p[0] * p[0], r1 = p[1] * p[1], r2 = p[2] * p[2], r3 = p[3] * p[3];
    float r4 = p[4] * p[4], r5 = p[5] * p[5], r6 = p[6] * p[6], r7 = p[7] * p[7];
    for (int i = 8; i < 128; i += 8) {
        r0 = r0 + p[i + 0] * p[i + 0];
        r1 = r1 + p[i + 1] * p[i + 1];
        r2 = r2 + p[i + 2] * p[i + 2];
        r3 = r3 + p[i + 3] * p[i + 3];
        r4 = r4 + p[i + 4] * p[i + 4];
        r5 = r5 + p[i + 5] * p[i + 5];
        r6 = r6 + p[i + 6] * p[i + 6];
        r7 = r7 + p[i + 7] * p[i + 7];
    }
    return ((r0 + r1) + (r2 + r3)) + ((r4 + r5) + (r6 + r7));
}

__device__ __forceinline__ float np_pairwise256_sumsq(const float* a) {
    #pragma clang fp contract(off)
    float s0 = np_block128_sumsq(a);
    float s1 = np_block128_sumsq(a + 128);
    return s0 + s1;
}

// ---------------------------------------------------------------------------
// Kernel 1: per-row sum of squares, numpy-pairwise-exact (unchanged, verified)
// ---------------------------------------------------------------------------
__global__ __launch_bounds__(256) void rowsumsq(const float* __restrict__ A,
                                                float* __restrict__ out) {
    __shared__ __align__(16) float sA[64][RSTRIDE];
    const int tid = threadIdx.x;
    const int base = blockIdx.x * 64;
    #pragma unroll
    for (int i = 0; i < 16; ++i) {
        int g = i * 256 + tid;
        int row = g >> 6, d4 = g & 63;
        float4 v = reinterpret_cast<const float4*>(A)[(size_t)(base + row) * (DD / 4) + d4];
        *reinterpret_cast<float4*>(&sA[row][d4 * 4]) = v;
    }
    __syncthreads();
    if (tid < 64) out[base + tid] = np_pairwise256_sumsq(sA[tid]);
}

// ---------------------------------------------------------------------------
// Kernel 1b: codebook transpose into d4-plane-major layout (R6, verified).
//   CBt[p*8192 + col] (float4) = CB[col][4p .. 4p+3]   (p = 0..63)
//   Bit-exact copy; enables coalesced per-lane codebook reads.
//   CBt lives in out+OUT_Q scratch; vq_gather overwrites all of it after.
// ---------------------------------------------------------------------------
__global__ __launch_bounds__(256) void cb_transpose(const float* __restrict__ CB,
                                                    float4* __restrict__ CBt) {
    const int id = blockIdx.x * 256 + threadIdx.x;   // 0 .. 64*8192-1
    const int p   = id >> 13;
    const int col = id & (KK - 1);
    CBt[id] = *reinterpret_cast<const float4*>(CB + (size_t)col * DD + p * 4);
}

// ---------------------------------------------------------------------------
// Kernel 2: main VQ distance+argmin — barrier-free streaming (R6, WIN) plus:
//   ROUND-7 (a): X via SCALAR loads. X values are wave-uniform (the wave's 8
//     rows); base pointer built from readfirstlane-derived indices -> hipcc
//     emits s_load_dwordx4 (scalar cache, zero VALU issue). Deletes the 32
//     v_readlane + 1 vector load per d4-step (~12% of VALU issue in R6).
//     Values are bit-identical (same addresses); fma chains untouched.
//   ROUND-7 (b): K-split 2-way for TLP. R6 was grid-limited to 8 waves/CU
//     (2048 waves, 18.5% stall). 1024 blocks x 4 waves = 16 waves/CU; wave =
//     8 rows x 4096 cols (group g: chunks g*8..g*8+7). Merge = R3/R5-verified
//     strict-less (group 0 owns lower cols -> first-index ties exact).
//     NO launch_bounds arg2 (the R0-R5 law: arg2 caps VGPR at 256/arg2 AND
//     pins residency); R6 proved no-arg2 leaves regalloc free (124) and
//     VGPR<=128 admits 4 waves/SIMD in HW (m69). cc processed in 2 halves
//     of 4 (legal: only per-(rr,j) d-chains are order-constrained) to halve
//     cc live registers and protect the <=128 budget.
//   Per-(row,col) fp32 fma chain d=0..255 in x/y/z/w order, score
//   fl(fl(x2+c2)-2m), first-index ties, butterfly argmin: all unchanged.
// ---------------------------------------------------------------------------
__global__ __launch_bounds__(256) void vq_main(const float* __restrict__ X,
                                               const float4* __restrict__ CBt,
                                               const float* __restrict__ c2,
                                               const float* __restrict__ x2,
                                               const float* __restrict__ mask,
                                               float* __restrict__ out,
                                               float* __restrict__ hist) {
    __shared__ float gbest[2][MT];
    __shared__ int   gidx[2][MT];

    const int tid  = threadIdx.x;
    const int lane = tid & 63;
    const int wid  = tid >> 6;                                  // 0..3
    const int widu = __builtin_amdgcn_readfirstlane(wid);       // uniform copy
    const int g    = wid >> 1;        // col-group (0: cols 0..4095, 1: 4096..8191)
    const int gu   = widu >> 1;
    const int wg   = wid & 1;         // row-group (8 rows each)
    const int wgu  = widu & 1;
    const int block_row = blockIdx.x * MT;

    // uniform X row base -> scalar loads (s_load) in the hot loop
    const float* xr = X + (size_t)(block_row + wgu * RPW) * DD;

    // row constants (bit-identical to numpy's x2)
    float x2r[RPW];
    #pragma unroll
    for (int rr = 0; rr < RPW; ++rr) x2r[rr] = x2[block_row + wg * RPW + rr];

    float best[RPW];
    int   besti[RPW];
    #pragma unroll
    for (int rr = 0; rr < RPW; ++rr) { best[rr] = 3.4e38f; besti[rr] = 0; }

    const float4* cbt_lane = CBt + lane;      // per-lane column offset

    for (int ch = 0; ch < NCHG; ++ch) {
        const int chg = gu * NCHG + ch;       // global chunk id (uniform)
        float c2v[8];
        #pragma unroll
        for (int j = 0; j < 8; ++j) c2v[j] = c2[chg * NT + lane + 64 * j];

        float acc[8][8];
        #pragma unroll
        for (int rr = 0; rr < 8; ++rr)
            #pragma unroll
            for (int j = 0; j < 8; ++j) acc[rr][j] = 0.0f;

        const float4* cbase = cbt_lane + (size_t)chg * NT;   // plane 0, this chunk

        for (int b = 0; b < 8; ++b) {               // d4 super-blocks (not unrolled)
            #pragma unroll
            for (int t = 0; t < 8; ++t) {
                const int p = b * 8 + t;            // d4 plane index 0..63
                const float4* src = cbase + (size_t)p * KK;
                #pragma unroll
                for (int jh = 0; jh < 2; ++jh) {    // two j-halves: cc regs 32->16
                    float4 cc[4];
                    #pragma unroll
                    for (int j = 0; j < 4; ++j) cc[j] = src[64 * (jh * 4 + j)];
                    #pragma unroll
                    for (int rr = 0; rr < 8; ++rr) {
                        // wave-uniform scalars (s_load path); same values as R6
                        const float sx = xr[rr * DD + p * 4 + 0];
                        const float sy = xr[rr * DD + p * 4 + 1];
                        const float sz = xr[rr * DD + p * 4 + 2];
                        const float sw = xr[rr * DD + p * 4 + 3];
                        #pragma unroll
                        for (int j = 0; j < 4; ++j) {
                            float& a = acc[rr][jh * 4 + j];
                            a = fmaf(sx, cc[j].x, a);
                            a = fmaf(sy, cc[j].y, a);
                            a = fmaf(sz, cc[j].z, a);
                            a = fmaf(sw, cc[j].w, a);
                        }
                    }
                }
            }
        }

        // ---- fp32 distance exactly as numpy, then argmin (first-index ties) ----
        #pragma unroll
        for (int rr = 0; rr < 8; ++rr) {
            #pragma unroll
            for (int j = 0; j < 8; ++j) {
                const int col = chg * NT + lane + 64 * j;
                float t1 = x2r[rr] + c2v[j];
                float sc = t1 - 2.0f * acc[rr][j];
                if (sc < best[rr] || (sc == best[rr] && col < besti[rr])) {
                    best[rr] = sc; besti[rr] = col;
                }
            }
        }
    }

    // ---- per-row argmin across the wave's 64 lanes (xor butterfly) ----
    #pragma unroll
    for (int rr = 0; rr < RPW; ++rr) {
        float b = best[rr];
        int  bi = besti[rr];
        #pragma unroll
        for (int m = 32; m > 0; m >>= 1) {
            float b2 = __shfl_xor(b, m, 64);
            int   i2 = __shfl_xor(bi, m, 64);
            if (b2 < b || (b2 == b && i2 < bi)) { b = b2; bi = i2; }
        }
        if (lane == 0) {
            gbest[g][wg * RPW + rr] = b;
            gidx [g][wg * RPW + rr] = bi;
        }
    }
    __syncthreads();   // the only block-wide barrier

    // ---- cross-group merge: group 0 has lower cols, so tie -> group 0 ----
    if (tid < MT) {
        const float b0 = gbest[0][tid], b1 = gbest[1][tid];
        const int bi = (b1 < b0) ? gidx[1][tid] : gidx[0][tid];
        out[OUT_IDS + block_row + tid] = (float)bi;   // exact integer in float
        atomicAdd(&hist[bi], mask[block_row + tid]);  // mask=1.0 -> order-exact
    }
}

// ---------------------------------------------------------------------------
// Kernel 2b: gather + MSE partials. 512 blocks x 256 threads, VERBATIM the
//   verified R0 epilogue -> partial[512] and outq/outst bit-identical.
//   Overwrites the CBt scratch region entirely.
// ---------------------------------------------------------------------------
__global__ __launch_bounds__(256) void vq_gather(const float* __restrict__ X,
                                                 const float* __restrict__ CB,
                                                 float* __restrict__ out,
                                                 float* __restrict__ partial) {
    __shared__ int   row_id[32];
    __shared__ float wsum[4];
    const int tid  = threadIdx.x;
    const int lane = tid & 63;
    const int wid  = tid >> 6;
    const int block_row = blockIdx.x * 32;

    if (tid < 32) row_id[tid] = (int)out[OUT_IDS + block_row + tid];
    __syncthreads();

    float msep = 0.0f;
    float* outq  = out + OUT_Q;
    float* outst = out + OUT_ST;
    #pragma unroll
    for (int i = 0; i < 8; ++i) {
        int g2 = i * 256 + tid;         // 0..2047 covers 32 rows x 64 float4
        int row = g2 >> 6;
        int d4  = g2 & 63;
        int id  = row_id[row];
        float4 q = reinterpret_cast<const float4*>(CB)[(size_t)id * (DD / 4) + d4];
        float4 x = reinterpret_cast<const float4*>(X)[(size_t)(block_row + row) * (DD / 4) + d4];
        float4 st;
        st.x = x.x + (q.x - x.x);
        st.y = x.y + (q.y - x.y);
        st.z = x.z + (q.z - x.z);
        st.w = x.w + (q.w - x.w);
        float dx = x.x - q.x; msep = fmaf(dx, dx, msep);
        dx = x.y - q.y; msep = fmaf(dx, dx, msep);
        dx = x.z - q.z; msep = fmaf(dx, dx, msep);
        dx = x.w - q.w; msep = fmaf(dx, dx, msep);
        size_t o = (size_t)(block_row + row) * (DD / 4) + d4;
        reinterpret_cast<float4*>(outq)[o]  = q;
        reinterpret_cast<float4*>(outst)[o] = st;
    }
    #pragma unroll
    for (int off = 32; off > 0; off >>= 1) msep += __shfl_down(msep, off, 64);
    if (lane == 0) wsum[wid] = msep;
    __syncthreads();
    if (tid == 0) partial[blockIdx.x] = wsum[0] + wsum[1] + wsum[2] + wsum[3];
}

// ---------------------------------------------------------------------------
// Kernel 3: finalize losses + perplexity (double precision, single block)
// ---------------------------------------------------------------------------
__global__ __launch_bounds__(256) void vq_finalize(const float* __restrict__ partial,
                                                   const float* __restrict__ hist,
                                                   float* __restrict__ out) {
    __shared__ double red[256];
    const int tid = threadIdx.x;

    double ps = 0.0;
    for (int j = tid; j < NBLOCKS; j += 256) ps += (double)partial[j];
    red[tid] = ps;
    __syncthreads();
    for (int s = 128; s > 0; s >>= 1) {
        if (tid < s) red[tid] += red[tid + s];
        __syncthreads();
    }
    double mse_sum = red[0];
    __syncthreads();

    double hs = 0.0;
    for (int j = tid; j < KK; j += 256) hs += (double)hist[j];
    red[tid] = hs;
    __syncthreads();
    for (int s = 128; s > 0; s >>= 1) {
        if (tid < s) red[tid] += red[tid + s];
        __syncthreads();
    }
    double denom = red[0] > 1.0 ? red[0] : 1.0;
    __syncthreads();

    double ent = 0.0;
    for (int j = tid; j < KK; j += 256) {
        double p = (double)hist[j] / denom;
        ent += p * log(p + 1e-8);
    }
    red[tid] = ent;
    __syncthreads();
    for (int s = 128; s > 0; s >>= 1) {
        if (tid < s) red[tid] += red[tid + s];
        __syncthreads();
    }

    if (tid == 0) {
        double mse = mse_sum / (double)((size_t)NN * DD);
        out[OUT_COMMIT] = (float)(mse * 0.25);
        out[OUT_CBL]    = (float)mse;
        out[OUT_PERP]   = (float)exp(-red[0]);
    }
}

// ---------------------------------------------------------------------------
extern "C" void kernel_launch(void* const* d_in, const int* in_sizes, int n_in,
                              void* d_out, int out_size, void* d_ws, size_t ws_size,
                              hipStream_t stream) {
    const float* latents = (const float*)d_in[0];   // [16,1024,256]
    const float* mask    = (const float*)d_in[1];   // [16,1024]
    const float* cb      = (const float*)d_in[2];   // [8192,256]
    float* out = (float*)d_out;

    // workspace layout (floats): hist[8192] | partial[512] | c2[8192] | x2[16384]
    float* hist    = (float*)d_ws;
    float* partial = hist + KK;
    float* c2      = partial + NBLOCKS;
    float* x2      = c2 + KK;

    // transposed-codebook scratch lives in the out buffer's OUT_Q region
    // (2M float4 = 8MB); vq_gather later overwrites all of it.
    float4* cbt = reinterpret_cast<float4*>(out + OUT_Q);

    hipMemsetAsync(d_ws, 0, KK * sizeof(float), stream);    // zero histogram
    rowsumsq<<<KK / 64, 256, 0, stream>>>(cb, c2);           // numpy-exact |c|^2
    rowsumsq<<<NN / 64, 256, 0, stream>>>(latents, x2);      // numpy-exact |x|^2
    cb_transpose<<<(64 * KK) / 256, 256, 0, stream>>>(cb, cbt);
    vq_main<<<NBM, 256, 0, stream>>>(latents, cbt, c2, x2, mask, out, hist);
    vq_gather<<<NBLOCKS, 256, 0, stream>>>(latents, cb, out, partial);
    vq_finalize<<<1, 256, 0, stream>>>(partial, hist, out);
}